// Round 1
// baseline (451.410 us; speedup 1.0000x reference)
//
#include <hip/hip_runtime.h>

// GroupATTBLK: with F == FS == 160, AvgPool collapses F to F'=1, so the final
// softmax (over the F' axis) is over a singleton axis -> mask == 1.0 exactly.
// Therefore out[b,c,t,f,0] = sum_d x[b,c,t,f,d]. D=4 is the stride-1 axis of
// x, so each output element is the sum of 4 consecutive floats: one float4
// load + one float store per output element. Pure HBM-bound streaming kernel.

__global__ void __launch_bounds__(256)
sum_last4_kernel(const float4* __restrict__ x, float* __restrict__ out, int n) {
    int i = blockIdx.x * blockDim.x + threadIdx.x;
    if (i < n) {
        float4 v = x[i];                 // 16 B coalesced: 1 KiB per wave per load
        out[i] = (v.x + v.y) + (v.z + v.w);
    }
}

extern "C" void kernel_launch(void* const* d_in, const int* in_sizes, int n_in,
                              void* d_out, int out_size, void* d_ws, size_t ws_size,
                              hipStream_t stream) {
    const float4* x = (const float4*)d_in[0];   // x: [B,C,T,F,D] fp32, D=4 innermost
    float* out = (float*)d_out;                 // out: [B,C,T,F,1] fp32

    const int n = out_size;                     // 4*64*512*160 = 20,971,520
    const int threads = 256;
    const int blocks = (n + threads - 1) / threads;
    sum_last4_kernel<<<blocks, threads, 0, stream>>>(x, out, n);
}